// Round 3
// baseline (828.703 us; speedup 1.0000x reference)
//
#include <hip/hip_runtime.h>
#include <hip/hip_bf16.h>

#define HDIM 128
#define NSTAGE 7

typedef __bf16 bf16x8 __attribute__((ext_vector_type(8)));
typedef __bf16 bf16x4 __attribute__((ext_vector_type(4)));
typedef float floatx16 __attribute__((ext_vector_type(16)));
typedef float floatx4 __attribute__((ext_vector_type(4)));

__device__ __forceinline__ float silu_f(float x) {
    return x * __builtin_amdgcn_rcpf(1.0f + __expf(-x));
}

// Weights -> bf16, stage order W1[0],W2[0],W1[1],W2[1],W1[2],W2[2],Wlin.
// XOR swizzle on 16B chunks: [m][k] -> m*128 + ((k>>3)^(m&7))*8 + (k&7).
__global__ void convert_weights(const float* __restrict__ W1,
                                const float* __restrict__ W2,
                                const float* __restrict__ Wlin,
                                __bf16* __restrict__ dst) {
    int idx = blockIdx.x * blockDim.x + threadIdx.x;
    if (idx >= NSTAGE * HDIM * HDIM) return;
    int s    = idx >> 14;
    int rem  = idx & 16383;
    int mrow = rem >> 7;
    int k    = rem & 127;
    const float* src;
    if (s == 6) src = Wlin;
    else {
        int l = s >> 1;
        src = ((s & 1) ? W2 : W1) + l * HDIM * HDIM;
    }
    float v = src[mrow * HDIM + k];
    int dsti = (s << 14) + (mrow << 7) + ((((k >> 3) ^ (mrow & 7)) << 3) | (k & 7));
    dst[dsti] = (__bf16)v;
}

// ---- counting sort of edges by target node ----
__global__ void hist_kernel(const int* __restrict__ tgt, int* __restrict__ hist, int E) {
    int e = blockIdx.x * blockDim.x + threadIdx.x;
    if (e < E) atomicAdd(&hist[tgt[e]], 1);
}

// single block, 1024 threads: exclusive prefix sum of hist[0..N) -> cursor
__global__ __launch_bounds__(1024) void scan_kernel(const int* __restrict__ hist,
                                                    int* __restrict__ cursor, int N) {
    __shared__ int part[1024];
    int t = threadIdx.x;
    int per = (N + 1023) >> 10;
    int lo = t * per, hi = min(lo + per, N);
    int s = 0;
    for (int i = lo; i < hi; ++i) s += hist[i];
    part[t] = s;
    __syncthreads();
    for (int d = 1; d < 1024; d <<= 1) {
        int v = (t >= d) ? part[t - d] : 0;
        __syncthreads();
        part[t] += v;
        __syncthreads();
    }
    int off = (t == 0) ? 0 : part[t - 1];
    for (int i = lo; i < hi; ++i) { cursor[i] = off; off += hist[i]; }
}

__global__ void scatter_perm(const int* __restrict__ tgt, int* __restrict__ cursor,
                             int* __restrict__ perm, int* __restrict__ snode, int E) {
    int e = blockIdx.x * blockDim.x + threadIdx.x;
    if (e < E) {
        int node = tgt[e];
        int pos = atomicAdd(&cursor[node], 1);
        perm[pos] = e;
        snode[pos] = node;
    }
}

// One wave owns 32 (sorted-order) edges end-to-end; residual X in fp32 regs.
// Matmuls transposed: D[feat][edge] via mfma_f32_32x32x16_bf16.
// C/D: edge=lane&31, feat=mb*32+(reg&3)+8*(reg>>2)+4*(lane>>5).
// Activation LDS: per edge-row stride 136 bf16, 16B-granule rotation swizzle.
// Epilogue: Y transposed through LDS; edges sorted by node -> segmented
// register accumulation, ~1.6 atomic row-writes per wave instead of 32.
__global__ __launch_bounds__(256, 2) void fused_mlp_scatter(
    const float* __restrict__ m,
    const int* __restrict__ perm,
    const int* __restrict__ snode,
    const __bf16* __restrict__ wmats,
    const float* __restrict__ b1,
    const float* __restrict__ b2,
    const float* __restrict__ blin,
    float* __restrict__ out,
    int E, int ntiles)
{
    __shared__ __align__(16) char smem[67584];
    __bf16* wlds   = (__bf16*)smem;                  // 32 KB
    __bf16* actAll = (__bf16*)(smem + 32768);        // 4*32*136 bf16
    float*  ybuf   = (float*)smem;                   // 4*32*132 f32 (overlay)

    const int tid  = threadIdx.x;
    const int w    = tid >> 6;
    const int lane = tid & 63;
    const int l31  = lane & 31;
    const int half = lane >> 5;

    const int tile    = blockIdx.x * 4 + w;
    const bool activeW = (tile < ntiles);
    const int pos = tile * 32 + l31;
    const bool evalid = activeW && (pos < E);

    int eidx = 0, mynode = 0;
    if (evalid) { eidx = perm[pos]; mynode = snode[pos]; }

    floatx4 X[4][4];
    floatx4 Yv[4][4];
    __bf16* actw = actAll + (w * 32 + l31) * 136;

    #define ACT_OFF(f) (((((((f) >> 4) + l31) & 7)) << 4) | ((f) & 15))

    if (activeW) {
        const float* mrow = m + (size_t)eidx * HDIM;
        for (int mb = 0; mb < 4; ++mb)
            for (int q = 0; q < 4; ++q) {
                int f0 = mb * 32 + q * 8 + half * 4;
                X[mb][q] = *(const floatx4*)(mrow + f0);
            }
        for (int mb = 0; mb < 4; ++mb)
            for (int q = 0; q < 4; ++q) {
                int f0 = mb * 32 + q * 8 + half * 4;
                bf16x4 v;
                for (int j = 0; j < 4; ++j) v[j] = (__bf16)silu_f(X[mb][q][j]);
                *(bf16x4*)(actw + ACT_OFF(f0)) = v;
            }
    }

    for (int s = 0; s < NSTAGE; ++s) {
        __syncthreads();
        {
            const __bf16* wsrc = wmats + (s << 14);
            for (int i = 0; i < 8; ++i) {
                int off = i * 2048 + tid * 8;
                *(bf16x8*)(&wlds[off]) = *(const bf16x8*)(wsrc + off);
            }
        }
        __syncthreads();
        if (!activeW) continue;

        floatx16 acc[4];
        for (int mb = 0; mb < 4; ++mb)
            for (int r = 0; r < 16; ++r) acc[mb][r] = 0.0f;

        for (int ks = 0; ks < 8; ++ks) {
            bf16x8 bfrag = *(const bf16x8*)(actw + ((((ks + l31) & 7) << 4) + half * 8));
            int krow = ks * 2 + half;
            for (int mb = 0; mb < 4; ++mb) {
                int mr = mb * 32 + l31;
                bf16x8 afrag = *(const bf16x8*)(&wlds[(mr << 7) + ((krow ^ (mr & 7)) << 3)]);
                acc[mb] = __builtin_amdgcn_mfma_f32_32x32x16_bf16(afrag, bfrag, acc[mb], 0, 0, 0);
            }
        }

        if (s == 6) {
            for (int mb = 0; mb < 4; ++mb)
                for (int q = 0; q < 4; ++q) {
                    int f0 = mb * 32 + q * 8 + half * 4;
                    floatx4 bv = *(const floatx4*)(blin + f0);
                    for (int j = 0; j < 4; ++j)
                        Yv[mb][q][j] = silu_f(acc[mb][q * 4 + j] + bv[j]);
                }
        } else if ((s & 1) == 0) {
            const float* bias = b1 + (s >> 1) * HDIM;
            for (int mb = 0; mb < 4; ++mb)
                for (int q = 0; q < 4; ++q) {
                    int f0 = mb * 32 + q * 8 + half * 4;
                    floatx4 bv = *(const floatx4*)(bias + f0);
                    bf16x4 hv;
                    for (int j = 0; j < 4; ++j)
                        hv[j] = (__bf16)silu_f(acc[mb][q * 4 + j] + bv[j]);
                    *(bf16x4*)(actw + ACT_OFF(f0)) = hv;
                }
        } else {
            const float* bias = b2 + (s >> 1) * HDIM;
            for (int mb = 0; mb < 4; ++mb)
                for (int q = 0; q < 4; ++q) {
                    int f0 = mb * 32 + q * 8 + half * 4;
                    floatx4 bv = *(const floatx4*)(bias + f0);
                    bf16x4 xv;
                    for (int j = 0; j < 4; ++j) {
                        float nx = X[mb][q][j] + acc[mb][q * 4 + j] + bv[j];
                        X[mb][q][j] = nx;
                        xv[j] = (__bf16)((s == 5) ? nx : silu_f(nx));
                    }
                    *(bf16x4*)(actw + ACT_OFF(f0)) = xv;
                }
        }
    }

    // ---- epilogue: transpose Y through LDS, segmented accumulate, scatter ----
    __syncthreads();
    if (activeW) {
        float* yrow = ybuf + (w * 32 + l31) * 132;
        for (int mb = 0; mb < 4; ++mb)
            for (int q = 0; q < 4; ++q) {
                int f0 = mb * 32 + q * 8 + half * 4;
                *(floatx4*)(yrow + f0) = Yv[mb][q];
            }
    }
    __syncthreads();
    if (activeW) {
        const float* yb = ybuf + w * 32 * 132;
        const int ebase = tile * 32;
        const int cnt = min(32, E - ebase);
        int cur = __builtin_amdgcn_readlane(mynode, 0);
        float a0 = 0.f, a1 = 0.f;
        for (int e = 0; e < cnt; ++e) {
            int node = __builtin_amdgcn_readlane(mynode, e);
            if (node != cur) {
                float* op = out + (size_t)cur * HDIM;
                unsafeAtomicAdd(op + lane, a0);
                unsafeAtomicAdd(op + 64 + lane, a1);
                cur = node; a0 = 0.f; a1 = 0.f;
            }
            a0 += yb[e * 132 + lane];
            a1 += yb[e * 132 + 64 + lane];
        }
        float* op = out + (size_t)cur * HDIM;
        unsafeAtomicAdd(op + lane, a0);
        unsafeAtomicAdd(op + 64 + lane, a1);
    }
    #undef ACT_OFF
}

extern "C" void kernel_launch(void* const* d_in, const int* in_sizes, int n_in,
                              void* d_out, int out_size, void* d_ws, size_t ws_size,
                              hipStream_t stream) {
    const float* m      = (const float*)d_in[0];
    const int* edge_idx = (const int*)d_in[1];
    const float* W1     = (const float*)d_in[3];
    const float* b1     = (const float*)d_in[4];
    const float* W2     = (const float*)d_in[5];
    const float* b2     = (const float*)d_in[6];
    const float* Wlin   = (const float*)d_in[7];
    const float* blin   = (const float*)d_in[8];

    int E = in_sizes[0] / HDIM;
    int N = out_size / HDIM;
    const int* tgt = edge_idx + E;

    // workspace layout
    char* ws = (char*)d_ws;
    __bf16* wbf   = (__bf16*)ws;                        // 229376 B
    int*    hist  = (int*)(ws + 229376);                // N*4 (pad 40960)
    int*    cursor= (int*)(ws + 229376 + 40960);        // N*4 (pad 40960)
    int*    perm  = (int*)(ws + 229376 + 81920);        // E*4
    int*    snode = (int*)(ws + 229376 + 81920 + 2000000); // E*4

    hipMemsetAsync(d_out, 0, (size_t)out_size * sizeof(float), stream);
    hipMemsetAsync(hist, 0, (size_t)N * sizeof(int), stream);

    convert_weights<<<(NSTAGE * HDIM * HDIM + 255) / 256, 256, 0, stream>>>(W1, W2, Wlin, wbf);
    hist_kernel<<<(E + 255) / 256, 256, 0, stream>>>(tgt, hist, E);
    scan_kernel<<<1, 1024, 0, stream>>>(hist, cursor, N);
    scatter_perm<<<(E + 255) / 256, 256, 0, stream>>>(tgt, cursor, perm, snode, E);

    int ntiles  = (E + 31) / 32;
    int nblocks = (ntiles + 3) / 4;
    fused_mlp_scatter<<<nblocks, 256, 0, stream>>>(m, perm, snode, wbf, b1, b2, blin,
                                                   (float*)d_out, E, ntiles);
}

// Round 4
// 674.396 us; speedup vs baseline: 1.2288x; 1.2288x over previous
//
#include <hip/hip_runtime.h>
#include <hip/hip_bf16.h>

#define HDIM 128
#define NSTAGE 7

typedef __bf16 bf16x8 __attribute__((ext_vector_type(8)));
typedef __bf16 bf16x4 __attribute__((ext_vector_type(4)));
typedef float floatx16 __attribute__((ext_vector_type(16)));
typedef float floatx4 __attribute__((ext_vector_type(4)));

__device__ __forceinline__ float silu_f(float x) {
    return x * __builtin_amdgcn_rcpf(1.0f + __expf(-x));
}

// Weights -> bf16, stage order W1[0],W2[0],W1[1],W2[1],W1[2],W2[2],Wlin.
// XOR swizzle on 16B chunks: [m][k] -> m*128 + ((k>>3)^(m&7))*8 + (k&7).
__global__ void convert_weights(const float* __restrict__ W1,
                                const float* __restrict__ W2,
                                const float* __restrict__ Wlin,
                                __bf16* __restrict__ dst) {
    int idx = blockIdx.x * blockDim.x + threadIdx.x;
    if (idx >= NSTAGE * HDIM * HDIM) return;
    int s    = idx >> 14;
    int rem  = idx & 16383;
    int mrow = rem >> 7;
    int k    = rem & 127;
    const float* src;
    if (s == 6) src = Wlin;
    else {
        int l = s >> 1;
        src = ((s & 1) ? W2 : W1) + l * HDIM * HDIM;
    }
    float v = src[mrow * HDIM + k];
    int dsti = (s << 14) + (mrow << 7) + ((((k >> 3) ^ (mrow & 7)) << 3) | (k & 7));
    dst[dsti] = (__bf16)v;
}

// ---- counting sort of edges by target node ----
__global__ void hist_kernel(const int* __restrict__ tgt, int* __restrict__ hist, int E) {
    int e = blockIdx.x * blockDim.x + threadIdx.x;
    if (e < E) atomicAdd(&hist[tgt[e]], 1);
}

__global__ __launch_bounds__(1024) void scan_kernel(const int* __restrict__ hist,
                                                    int* __restrict__ cursor, int N) {
    __shared__ int part[1024];
    int t = threadIdx.x;
    int per = (N + 1023) >> 10;
    int lo = t * per, hi = min(lo + per, N);
    int s = 0;
    for (int i = lo; i < hi; ++i) s += hist[i];
    part[t] = s;
    __syncthreads();
    for (int d = 1; d < 1024; d <<= 1) {
        int v = (t >= d) ? part[t - d] : 0;
        __syncthreads();
        part[t] += v;
        __syncthreads();
    }
    int off = (t == 0) ? 0 : part[t - 1];
    for (int i = lo; i < hi; ++i) { cursor[i] = off; off += hist[i]; }
}

__global__ void scatter_perm(const int* __restrict__ tgt, int* __restrict__ cursor,
                             int* __restrict__ perm, int* __restrict__ snode, int E) {
    int e = blockIdx.x * blockDim.x + threadIdx.x;
    if (e < E) {
        int node = tgt[e];
        int pos = atomicAdd(&cursor[node], 1);
        perm[pos] = e;
        snode[pos] = node;
    }
}

// One wave owns 32 sorted-order edges end-to-end; residual X in fp32 regs.
// Matmuls transposed: D[feat][edge] via mfma_f32_32x32x16_bf16.
// C/D: edge=lane&31, feat=mb*32+(reg&3)+8*(reg>>2)+4*(lane>>5).
// Activation LDS: per edge-row stride 136 bf16, 16B-granule rotation swizzle.
// Stage loop fully unrolled; epilogue applies blin+silu IN-PLACE into acc
// (no Yv array -> no scratch spills), then transposes through ybuf (overlay)
// and does segmented per-node atomic row-writes (~1.6 per wave).
__global__ __launch_bounds__(256, 2) void fused_mlp_scatter(
    const float* __restrict__ m,
    const int* __restrict__ perm,
    const int* __restrict__ snode,
    const __bf16* __restrict__ wmats,
    const float* __restrict__ b1,
    const float* __restrict__ b2,
    const float* __restrict__ blin,
    float* __restrict__ out,
    int E, int ntiles)
{
    __shared__ __align__(16) char smem[67584];
    __bf16* wlds   = (__bf16*)smem;                  // 32 KB
    __bf16* actAll = (__bf16*)(smem + 32768);        // 4*32*136 bf16
    float*  ybuf   = (float*)smem;                   // 4*32*132 f32 (overlay)

    const int tid  = threadIdx.x;
    const int w    = tid >> 6;
    const int lane = tid & 63;
    const int l31  = lane & 31;
    const int half = lane >> 5;

    const int tile    = blockIdx.x * 4 + w;
    const bool activeW = (tile < ntiles);
    const int pos = tile * 32 + l31;
    const bool evalid = activeW && (pos < E);

    int eidx = 0, mynode = 0;
    if (evalid) { eidx = perm[pos]; mynode = snode[pos]; }

    floatx4 X[4][4];
    floatx16 acc[4];
    __bf16* actw = actAll + (w * 32 + l31) * 136;

    #define ACT_OFF(f) (((((((f) >> 4) + l31) & 7)) << 4) | ((f) & 15))

    if (activeW) {
        const float* mrow = m + (size_t)eidx * HDIM;
        #pragma unroll
        for (int mb = 0; mb < 4; ++mb)
            #pragma unroll
            for (int q = 0; q < 4; ++q) {
                int f0 = mb * 32 + q * 8 + half * 4;
                X[mb][q] = *(const floatx4*)(mrow + f0);
            }
        #pragma unroll
        for (int mb = 0; mb < 4; ++mb)
            #pragma unroll
            for (int q = 0; q < 4; ++q) {
                int f0 = mb * 32 + q * 8 + half * 4;
                bf16x4 v;
                for (int j = 0; j < 4; ++j) v[j] = (__bf16)silu_f(X[mb][q][j]);
                *(bf16x4*)(actw + ACT_OFF(f0)) = v;
            }
    }

    #pragma unroll
    for (int s = 0; s < NSTAGE; ++s) {
        __syncthreads();
        {
            const __bf16* wsrc = wmats + (s << 14);
            #pragma unroll
            for (int i = 0; i < 8; ++i) {
                int off = i * 2048 + tid * 8;
                *(bf16x8*)(&wlds[off]) = *(const bf16x8*)(wsrc + off);
            }
        }
        __syncthreads();
        if (!activeW) continue;

        #pragma unroll
        for (int mb = 0; mb < 4; ++mb)
            for (int r = 0; r < 16; ++r) acc[mb][r] = 0.0f;

        #pragma unroll
        for (int ks = 0; ks < 8; ++ks) {
            bf16x8 bfrag = *(const bf16x8*)(actw + ((((ks + l31) & 7) << 4) + half * 8));
            int krow = ks * 2 + half;
            #pragma unroll
            for (int mb = 0; mb < 4; ++mb) {
                int mr = mb * 32 + l31;
                bf16x8 afrag = *(const bf16x8*)(&wlds[(mr << 7) + ((krow ^ (mr & 7)) << 3)]);
                acc[mb] = __builtin_amdgcn_mfma_f32_32x32x16_bf16(afrag, bfrag, acc[mb], 0, 0, 0);
            }
        }

        if (s == 6) {
            // blin + silu IN-PLACE into acc (carried across the barrier below)
            #pragma unroll
            for (int mb = 0; mb < 4; ++mb)
                #pragma unroll
                for (int q = 0; q < 4; ++q) {
                    int f0 = mb * 32 + q * 8 + half * 4;
                    floatx4 bv = *(const floatx4*)(blin + f0);
                    for (int j = 0; j < 4; ++j)
                        acc[mb][q * 4 + j] = silu_f(acc[mb][q * 4 + j] + bv[j]);
                }
        } else if ((s & 1) == 0) {
            const float* bias = b1 + (s >> 1) * HDIM;
            #pragma unroll
            for (int mb = 0; mb < 4; ++mb)
                #pragma unroll
                for (int q = 0; q < 4; ++q) {
                    int f0 = mb * 32 + q * 8 + half * 4;
                    floatx4 bv = *(const floatx4*)(bias + f0);
                    bf16x4 hv;
                    for (int j = 0; j < 4; ++j)
                        hv[j] = (__bf16)silu_f(acc[mb][q * 4 + j] + bv[j]);
                    *(bf16x4*)(actw + ACT_OFF(f0)) = hv;
                }
        } else {
            const float* bias = b2 + (s >> 1) * HDIM;
            #pragma unroll
            for (int mb = 0; mb < 4; ++mb)
                #pragma unroll
                for (int q = 0; q < 4; ++q) {
                    int f0 = mb * 32 + q * 8 + half * 4;
                    floatx4 bv = *(const floatx4*)(bias + f0);
                    bf16x4 xv;
                    for (int j = 0; j < 4; ++j) {
                        float nx = X[mb][q][j] + acc[mb][q * 4 + j] + bv[j];
                        X[mb][q][j] = nx;
                        xv[j] = (__bf16)((s == 5) ? nx : silu_f(nx));
                    }
                    *(bf16x4*)(actw + ACT_OFF(f0)) = xv;
                }
        }
    }

    // ---- epilogue: all waves must be done with wlds/actAll before overlay ----
    __syncthreads();
    if (activeW) {
        float* yrow = ybuf + (w * 32 + l31) * 132;
        #pragma unroll
        for (int mb = 0; mb < 4; ++mb)
            #pragma unroll
            for (int q = 0; q < 4; ++q) {
                int f0 = mb * 32 + q * 8 + half * 4;
                floatx4 v;
                for (int j = 0; j < 4; ++j) v[j] = acc[mb][q * 4 + j];
                *(floatx4*)(yrow + f0) = v;
            }
        // wave-private from here: segmented accumulate + atomic row-writes
        const float* yb = ybuf + w * 32 * 132;
        const int ebase = tile * 32;
        const int cnt = min(32, E - ebase);
        int cur = __builtin_amdgcn_readlane(mynode, 0);
        float a0 = 0.f, a1 = 0.f;
        for (int e = 0; e < cnt; ++e) {
            int node = __builtin_amdgcn_readlane(mynode, e);
            if (node != cur) {
                float* op = out + (size_t)cur * HDIM;
                unsafeAtomicAdd(op + lane, a0);
                unsafeAtomicAdd(op + 64 + lane, a1);
                cur = node; a0 = 0.f; a1 = 0.f;
            }
            a0 += yb[e * 132 + lane];
            a1 += yb[e * 132 + 64 + lane];
        }
        float* op = out + (size_t)cur * HDIM;
        unsafeAtomicAdd(op + lane, a0);
        unsafeAtomicAdd(op + 64 + lane, a1);
    }
    #undef ACT_OFF
}

extern "C" void kernel_launch(void* const* d_in, const int* in_sizes, int n_in,
                              void* d_out, int out_size, void* d_ws, size_t ws_size,
                              hipStream_t stream) {
    const float* m      = (const float*)d_in[0];
    const int* edge_idx = (const int*)d_in[1];
    const float* W1     = (const float*)d_in[3];
    const float* b1     = (const float*)d_in[4];
    const float* W2     = (const float*)d_in[5];
    const float* b2     = (const float*)d_in[6];
    const float* Wlin   = (const float*)d_in[7];
    const float* blin   = (const float*)d_in[8];

    int E = in_sizes[0] / HDIM;
    int N = out_size / HDIM;
    const int* tgt = edge_idx + E;

    char* ws = (char*)d_ws;
    __bf16* wbf   = (__bf16*)ws;                           // 229376 B
    int*    hist  = (int*)(ws + 229376);                   // N*4 (pad 40960)
    int*    cursor= (int*)(ws + 229376 + 40960);           // N*4 (pad 40960)
    int*    perm  = (int*)(ws + 229376 + 81920);           // E*4
    int*    snode = (int*)(ws + 229376 + 81920 + 2000000); // E*4

    hipMemsetAsync(d_out, 0, (size_t)out_size * sizeof(float), stream);
    hipMemsetAsync(hist, 0, (size_t)N * sizeof(int), stream);

    convert_weights<<<(NSTAGE * HDIM * HDIM + 255) / 256, 256, 0, stream>>>(W1, W2, Wlin, wbf);
    hist_kernel<<<(E + 255) / 256, 256, 0, stream>>>(tgt, hist, E);
    scan_kernel<<<1, 1024, 0, stream>>>(hist, cursor, N);
    scatter_perm<<<(E + 255) / 256, 256, 0, stream>>>(tgt, cursor, perm, snode, E);

    int ntiles  = (E + 31) / 32;
    int nblocks = (ntiles + 3) / 4;
    fused_mlp_scatter<<<nblocks, 256, 0, stream>>>(m, perm, snode, wbf, b1, b2, blin,
                                                   (float*)d_out, E, ntiles);
}

// Round 5
// 671.926 us; speedup vs baseline: 1.2333x; 1.0037x over previous
//
#include <hip/hip_runtime.h>
#include <hip/hip_bf16.h>

#define HDIM 128
#define NSTAGE 7

typedef __bf16 bf16x8 __attribute__((ext_vector_type(8)));
typedef __bf16 bf16x4 __attribute__((ext_vector_type(4)));
typedef float floatx16 __attribute__((ext_vector_type(16)));
typedef float floatx4 __attribute__((ext_vector_type(4)));

__device__ __forceinline__ float silu_f(float x) {
    return x * __builtin_amdgcn_rcpf(1.0f + __expf(-x));
}

// Weights -> bf16, stage order W1[0],W2[0],W1[1],W2[1],W1[2],W2[2],Wlin.
// XOR swizzle on 16B chunks: [m][k] -> m*128 + ((k>>3)^(m&7))*8 + (k&7).
__global__ void convert_weights(const float* __restrict__ W1,
                                const float* __restrict__ W2,
                                const float* __restrict__ Wlin,
                                __bf16* __restrict__ dst) {
    int idx = blockIdx.x * blockDim.x + threadIdx.x;
    if (idx >= NSTAGE * HDIM * HDIM) return;
    int s    = idx >> 14;
    int rem  = idx & 16383;
    int mrow = rem >> 7;
    int k    = rem & 127;
    const float* src;
    if (s == 6) src = Wlin;
    else {
        int l = s >> 1;
        src = ((s & 1) ? W2 : W1) + l * HDIM * HDIM;
    }
    float v = src[mrow * HDIM + k];
    int dsti = (s << 14) + (mrow << 7) + ((((k >> 3) ^ (mrow & 7)) << 3) | (k & 7));
    dst[dsti] = (__bf16)v;
}

// ---- counting sort of edges by target node ----
__global__ void hist_kernel(const int* __restrict__ tgt, int* __restrict__ hist, int E) {
    int e = blockIdx.x * blockDim.x + threadIdx.x;
    if (e < E) atomicAdd(&hist[tgt[e]], 1);
}

__global__ __launch_bounds__(1024) void scan_kernel(const int* __restrict__ hist,
                                                    int* __restrict__ cursor, int N) {
    __shared__ int part[1024];
    int t = threadIdx.x;
    int per = (N + 1023) >> 10;
    int lo = t * per, hi = min(lo + per, N);
    int s = 0;
    for (int i = lo; i < hi; ++i) s += hist[i];
    part[t] = s;
    __syncthreads();
    for (int d = 1; d < 1024; d <<= 1) {
        int v = (t >= d) ? part[t - d] : 0;
        __syncthreads();
        part[t] += v;
        __syncthreads();
    }
    int off = (t == 0) ? 0 : part[t - 1];
    for (int i = lo; i < hi; ++i) { cursor[i] = off; off += hist[i]; }
}

__global__ void scatter_perm(const int* __restrict__ tgt, int* __restrict__ cursor,
                             int* __restrict__ perm, int* __restrict__ snode, int E) {
    int e = blockIdx.x * blockDim.x + threadIdx.x;
    if (e < E) {
        int node = tgt[e];
        int pos = atomicAdd(&cursor[node], 1);
        perm[pos] = e;
        snode[pos] = node;
    }
}

// One wave owns 32 sorted-order edges end-to-end; residual X in fp32 regs.
// Matmuls transposed: D[feat][edge] via mfma_f32_32x32x16_bf16.
// C/D: edge=lane&31, feat=mb*32+(reg&3)+8*(reg>>2)+4*(lane>>5).
// Activation LDS: per edge-row stride 136 bf16, 16B-granule rotation swizzle.
// W staging is SOFTWARE-PIPELINED through registers: stage s+1's 32 KB tile
// is global-loaded into 8 bf16x8 regs/thread during stage s's compute; the
// vmcnt drain lands a full compute-phase after issue instead of right before
// the barrier (removes per-stage L2-latency exposure on the critical path).
__global__ __launch_bounds__(256, 2) void fused_mlp_scatter(
    const float* __restrict__ m,
    const int* __restrict__ perm,
    const int* __restrict__ snode,
    const __bf16* __restrict__ wmats,
    const float* __restrict__ b1,
    const float* __restrict__ b2,
    const float* __restrict__ blin,
    float* __restrict__ out,
    int E, int ntiles)
{
    __shared__ __align__(16) char smem[67584];
    __bf16* wlds   = (__bf16*)smem;                  // 32 KB
    __bf16* actAll = (__bf16*)(smem + 32768);        // 4*32*136 bf16
    float*  ybuf   = (float*)smem;                   // 4*32*132 f32 (overlay)

    const int tid  = threadIdx.x;
    const int w    = tid >> 6;
    const int lane = tid & 63;
    const int l31  = lane & 31;
    const int half = lane >> 5;

    const int tile    = blockIdx.x * 4 + w;
    const bool activeW = (tile < ntiles);
    const int pos = tile * 32 + l31;
    const bool evalid = activeW && (pos < E);

    int eidx = 0, mynode = 0;
    if (evalid) { eidx = perm[pos]; mynode = snode[pos]; }

    floatx4 X[4][4];
    floatx16 acc[4];
    bf16x8 wpre[8];
    __bf16* actw = actAll + (w * 32 + l31) * 136;

    #define ACT_OFF(f) (((((((f) >> 4) + l31) & 7)) << 4) | ((f) & 15))

    // prefetch stage-0 W tile into registers (all 256 threads)
    #pragma unroll
    for (int i = 0; i < 8; ++i)
        wpre[i] = *(const bf16x8*)(wmats + i * 2048 + tid * 8);

    if (activeW) {
        const float* mrow = m + (size_t)eidx * HDIM;
        #pragma unroll
        for (int mb = 0; mb < 4; ++mb)
            #pragma unroll
            for (int q = 0; q < 4; ++q) {
                int f0 = mb * 32 + q * 8 + half * 4;
                X[mb][q] = *(const floatx4*)(mrow + f0);
            }
        #pragma unroll
        for (int mb = 0; mb < 4; ++mb)
            #pragma unroll
            for (int q = 0; q < 4; ++q) {
                int f0 = mb * 32 + q * 8 + half * 4;
                bf16x4 v;
                for (int j = 0; j < 4; ++j) v[j] = (__bf16)silu_f(X[mb][q][j]);
                *(bf16x4*)(actw + ACT_OFF(f0)) = v;
            }
    }

    #pragma unroll
    for (int s = 0; s < NSTAGE; ++s) {
        __syncthreads();   // all waves done reading wlds from previous stage
        #pragma unroll
        for (int i = 0; i < 8; ++i)
            *(bf16x8*)(&wlds[i * 2048 + tid * 8]) = wpre[i];
        __syncthreads();
        // issue next stage's W loads now; vmcnt drains during compute below
        if (s < NSTAGE - 1) {
            const __bf16* wsrc = wmats + ((s + 1) << 14);
            #pragma unroll
            for (int i = 0; i < 8; ++i)
                wpre[i] = *(const bf16x8*)(wsrc + i * 2048 + tid * 8);
        }
        if (!activeW) continue;

        #pragma unroll
        for (int mb = 0; mb < 4; ++mb)
            for (int r = 0; r < 16; ++r) acc[mb][r] = 0.0f;

        #pragma unroll
        for (int ks = 0; ks < 8; ++ks) {
            bf16x8 bfrag = *(const bf16x8*)(actw + ((((ks + l31) & 7) << 4) + half * 8));
            int krow = ks * 2 + half;
            #pragma unroll
            for (int mb = 0; mb < 4; ++mb) {
                int mr = mb * 32 + l31;
                bf16x8 afrag = *(const bf16x8*)(&wlds[(mr << 7) + ((krow ^ (mr & 7)) << 3)]);
                acc[mb] = __builtin_amdgcn_mfma_f32_32x32x16_bf16(afrag, bfrag, acc[mb], 0, 0, 0);
            }
        }

        if (s == 6) {
            // blin + silu IN-PLACE into acc (carried across the barrier below)
            #pragma unroll
            for (int mb = 0; mb < 4; ++mb)
                #pragma unroll
                for (int q = 0; q < 4; ++q) {
                    int f0 = mb * 32 + q * 8 + half * 4;
                    floatx4 bv = *(const floatx4*)(blin + f0);
                    for (int j = 0; j < 4; ++j)
                        acc[mb][q * 4 + j] = silu_f(acc[mb][q * 4 + j] + bv[j]);
                }
        } else if ((s & 1) == 0) {
            const float* bias = b1 + (s >> 1) * HDIM;
            #pragma unroll
            for (int mb = 0; mb < 4; ++mb)
                #pragma unroll
                for (int q = 0; q < 4; ++q) {
                    int f0 = mb * 32 + q * 8 + half * 4;
                    floatx4 bv = *(const floatx4*)(bias + f0);
                    bf16x4 hv;
                    for (int j = 0; j < 4; ++j)
                        hv[j] = (__bf16)silu_f(acc[mb][q * 4 + j] + bv[j]);
                    *(bf16x4*)(actw + ACT_OFF(f0)) = hv;
                }
        } else {
            const float* bias = b2 + (s >> 1) * HDIM;
            #pragma unroll
            for (int mb = 0; mb < 4; ++mb)
                #pragma unroll
                for (int q = 0; q < 4; ++q) {
                    int f0 = mb * 32 + q * 8 + half * 4;
                    floatx4 bv = *(const floatx4*)(bias + f0);
                    bf16x4 xv;
                    for (int j = 0; j < 4; ++j) {
                        float nx = X[mb][q][j] + acc[mb][q * 4 + j] + bv[j];
                        X[mb][q][j] = nx;
                        xv[j] = (__bf16)((s == 5) ? nx : silu_f(nx));
                    }
                    *(bf16x4*)(actw + ACT_OFF(f0)) = xv;
                }
        }
    }

    // ---- epilogue: all waves must be done with wlds/actAll before overlay ----
    __syncthreads();
    if (activeW) {
        float* yrow = ybuf + (w * 32 + l31) * 132;
        #pragma unroll
        for (int mb = 0; mb < 4; ++mb)
            #pragma unroll
            for (int q = 0; q < 4; ++q) {
                int f0 = mb * 32 + q * 8 + half * 4;
                floatx4 v;
                for (int j = 0; j < 4; ++j) v[j] = acc[mb][q * 4 + j];
                *(floatx4*)(yrow + f0) = v;
            }
        // wave-private from here: segmented accumulate + atomic row-writes
        const float* yb = ybuf + w * 32 * 132;
        const int ebase = tile * 32;
        const int cnt = min(32, E - ebase);
        int cur = __builtin_amdgcn_readlane(mynode, 0);
        float a0 = 0.f, a1 = 0.f;
        for (int e = 0; e < cnt; ++e) {
            int node = __builtin_amdgcn_readlane(mynode, e);
            if (node != cur) {
                float* op = out + (size_t)cur * HDIM;
                unsafeAtomicAdd(op + lane, a0);
                unsafeAtomicAdd(op + 64 + lane, a1);
                cur = node; a0 = 0.f; a1 = 0.f;
            }
            a0 += yb[e * 132 + lane];
            a1 += yb[e * 132 + 64 + lane];
        }
        float* op = out + (size_t)cur * HDIM;
        unsafeAtomicAdd(op + lane, a0);
        unsafeAtomicAdd(op + 64 + lane, a1);
    }
    #undef ACT_OFF
}

extern "C" void kernel_launch(void* const* d_in, const int* in_sizes, int n_in,
                              void* d_out, int out_size, void* d_ws, size_t ws_size,
                              hipStream_t stream) {
    const float* m      = (const float*)d_in[0];
    const int* edge_idx = (const int*)d_in[1];
    const float* W1     = (const float*)d_in[3];
    const float* b1     = (const float*)d_in[4];
    const float* W2     = (const float*)d_in[5];
    const float* b2     = (const float*)d_in[6];
    const float* Wlin   = (const float*)d_in[7];
    const float* blin   = (const float*)d_in[8];

    int E = in_sizes[0] / HDIM;
    int N = out_size / HDIM;
    const int* tgt = edge_idx + E;

    char* ws = (char*)d_ws;
    __bf16* wbf   = (__bf16*)ws;                           // 229376 B
    int*    hist  = (int*)(ws + 229376);                   // N*4 (pad 40960)
    int*    cursor= (int*)(ws + 229376 + 40960);           // N*4 (pad 40960)
    int*    perm  = (int*)(ws + 229376 + 81920);           // E*4
    int*    snode = (int*)(ws + 229376 + 81920 + 2000000); // E*4

    hipMemsetAsync(d_out, 0, (size_t)out_size * sizeof(float), stream);
    hipMemsetAsync(hist, 0, (size_t)N * sizeof(int), stream);

    convert_weights<<<(NSTAGE * HDIM * HDIM + 255) / 256, 256, 0, stream>>>(W1, W2, Wlin, wbf);
    hist_kernel<<<(E + 255) / 256, 256, 0, stream>>>(tgt, hist, E);
    scan_kernel<<<1, 1024, 0, stream>>>(hist, cursor, N);
    scatter_perm<<<(E + 255) / 256, 256, 0, stream>>>(tgt, cursor, perm, snode, E);

    int ntiles  = (E + 31) / 32;
    int nblocks = (ntiles + 3) / 4;
    fused_mlp_scatter<<<nblocks, 256, 0, stream>>>(m, perm, snode, wbf, b1, b2, blin,
                                                   (float*)d_out, E, ntiles);
}